// Round 1
// baseline (2128.438 us; speedup 1.0000x reference)
//
#include <hip/hip_runtime.h>
#include <math.h>

#define NQ    40000
#define EDIM  256
#define H2    512
#define BEVH  200
#define BEVW  200

enum { SRC_VAL = 0, SRC_IM2COL = 1, SRC_PLAIN = 2 };

#define BM 128
#define BN 64
#define BK 16

// ---------------------------------------------------------------------------
// prep: q2[n, 0:256] = pre (= sos ? query : pre_bev), q2[n, 256:512] = query+qpos
// ---------------------------------------------------------------------------
__global__ __launch_bounds__(256) void prep_kernel(
    const float* __restrict__ query, const float* __restrict__ qpos,
    const float* __restrict__ prebev, const unsigned char* __restrict__ sos,
    float* __restrict__ q2)
{
  int i = blockIdx.x * 256 + threadIdx.x;
  if (i >= NQ * EDIM) return;
  int n = i >> 8, e = i & 255;
  bool s = sos[0] != 0;
  float qv = query[i];
  float pre = s ? qv : prebev[i];
  q2[(size_t)n * H2 + e] = pre;
  q2[(size_t)n * H2 + 256 + e] = qv + qpos[i];
}

// ---------------------------------------------------------------------------
// reorder conv weights (co, ci, ky, kx) -> (co, tap, ci)  [tap = ky*3+kx]
// so im2col K index k = tap*512 + ci is contiguous in ci.
// ---------------------------------------------------------------------------
__global__ __launch_bounds__(256) void reorder_w_kernel(
    const float* __restrict__ w, float* __restrict__ wr, int CO)
{
  int i = blockIdx.x * 256 + threadIdx.x;
  if (i >= CO * 4608) return;
  int co = i / 4608;
  int r = i - co * 4608;
  int tap = r >> 9;
  int ci = r & 511;
  wr[i] = w[(size_t)co * 4608 + ci * 9 + tap];
}

// ---------------------------------------------------------------------------
// Tiled fp32 GEMM: C[M][N] = A[M][K] * B[N][K]^T + bias[N] (+ addend[M][N])
// BM=128, BN=64, BK=16; 256 threads; 8x4 micro-tile per thread.
// A source is templated:
//   SRC_VAL   : m = b*NQ+n ; b==0 -> q2[n, 0:256] (pre), b==1 -> query[n, :]
//   SRC_IM2COL: k = tap*512+ci ; value = q2[pixel(m,tap), ci] (0 if OOB)
//   SRC_PLAIN : A0[m*K + k]
// ---------------------------------------------------------------------------
template <int ASRC, bool ADD_IDENT>
__global__ __launch_bounds__(256) void gemm_kernel(
    const float* __restrict__ A0, const float* __restrict__ A1,
    const float* __restrict__ B, const float* __restrict__ bias,
    const float* __restrict__ addend, float* __restrict__ C,
    int M, int N, int K)
{
  __shared__ float As[BK][BM];
  __shared__ float Bs[BK][BN];
  int tid = threadIdx.x;
  int m0 = blockIdx.x * BM;
  int n0 = blockIdx.y * BN;
  int tx = tid & 15;        // N direction (x4)
  int ty = tid >> 4;        // M direction (x8)

  float acc[8][4];
#pragma unroll
  for (int i = 0; i < 8; i++)
#pragma unroll
    for (int j = 0; j < 4; j++) acc[i][j] = 0.f;

  int a_m = tid >> 1;            // 0..127
  int a_k = (tid & 1) * 8;       // 0 or 8
  int b_n = tid >> 2;            // 0..63
  int b_k = (tid & 3) * 4;       // 0,4,8,12

  for (int k0 = 0; k0 < K; k0 += BK) {
    float4 av0 = make_float4(0.f, 0.f, 0.f, 0.f);
    float4 av1 = av0;
    int mg = m0 + a_m;

    if constexpr (ASRC == SRC_IM2COL) {
      int tap = k0 >> 9;                // constant within a BK chunk (512%16==0)
      int ky = tap / 3 - 1;
      int kx = tap - (tap / 3) * 3 - 1;
      if (mg < M) {
        int y = mg / BEVW + ky;
        int x = mg - (mg / BEVW) * BEVW + kx;
        if (y >= 0 && y < BEVH && x >= 0 && x < BEVW) {
          const float* p = A0 + (size_t)(y * BEVW + x) * H2 + (k0 & 511) + a_k;
          av0 = *(const float4*)p;
          av1 = *(const float4*)(p + 4);
        }
      }
    } else if constexpr (ASRC == SRC_VAL) {
      int b = mg >= NQ;
      int n = mg - (b ? NQ : 0);
      const float* p = b ? (A1 + (size_t)n * EDIM + k0 + a_k)
                         : (A0 + (size_t)n * H2 + k0 + a_k);
      av0 = *(const float4*)p;
      av1 = *(const float4*)(p + 4);
    } else {
      if (mg < M) {
        const float* p = A0 + (size_t)mg * K + k0 + a_k;
        av0 = *(const float4*)p;
        av1 = *(const float4*)(p + 4);
      }
    }

    const float* pb = B + (size_t)(n0 + b_n) * K + k0 + b_k;
    float4 bv = *(const float4*)pb;

    __syncthreads();   // previous tile fully consumed
    As[a_k + 0][a_m] = av0.x;
    As[a_k + 1][a_m] = av0.y;
    As[a_k + 2][a_m] = av0.z;
    As[a_k + 3][a_m] = av0.w;
    As[a_k + 4][a_m] = av1.x;
    As[a_k + 5][a_m] = av1.y;
    As[a_k + 6][a_m] = av1.z;
    As[a_k + 7][a_m] = av1.w;
    Bs[b_k + 0][b_n] = bv.x;
    Bs[b_k + 1][b_n] = bv.y;
    Bs[b_k + 2][b_n] = bv.z;
    Bs[b_k + 3][b_n] = bv.w;
    __syncthreads();

#pragma unroll
    for (int kk = 0; kk < BK; kk++) {
      const float4 Av0 = *(const float4*)&As[kk][ty * 8];
      const float4 Av1 = *(const float4*)&As[kk][ty * 8 + 4];
      const float4 Bv  = *(const float4*)&Bs[kk][tx * 4];
      float a[8] = {Av0.x, Av0.y, Av0.z, Av0.w, Av1.x, Av1.y, Av1.z, Av1.w};
      float bb[4] = {Bv.x, Bv.y, Bv.z, Bv.w};
#pragma unroll
      for (int i = 0; i < 8; i++)
#pragma unroll
        for (int j = 0; j < 4; j++) acc[i][j] = fmaf(a[i], bb[j], acc[i][j]);
    }
  }

  float4 bvec = *(const float4*)&bias[n0 + tx * 4];
#pragma unroll
  for (int i = 0; i < 8; i++) {
    int mg = m0 + ty * 8 + i;
    if (mg < M) {
      float4 o = make_float4(acc[i][0] + bvec.x, acc[i][1] + bvec.y,
                             acc[i][2] + bvec.z, acc[i][3] + bvec.w);
      if constexpr (ADD_IDENT) {
        const float4 ad = *(const float4*)&addend[(size_t)mg * N + n0 + tx * 4];
        o.x += ad.x; o.y += ad.y; o.z += ad.z; o.w += ad.w;
      }
      *(float4*)&C[(size_t)mg * N + n0 + tx * 4] = o;
    }
  }
}

// ---------------------------------------------------------------------------
// sampling: per (n, h, d): softmax over P per (h, queue), bilinear-gather from
// valp, weight, sum over p, average queues. mid[n, h*32+d].
// ---------------------------------------------------------------------------
__global__ __launch_bounds__(256) void sample_kernel(
    const float* __restrict__ valp, const float* __restrict__ convoff,
    const float* __restrict__ convattn, const float* __restrict__ preref,
    const float* __restrict__ refp, float* __restrict__ mid)
{
  int n = blockIdx.x;
  int tid = threadIdx.x;
  int h = tid >> 5, d = tid & 31;
  float acc = 0.f;

#pragma unroll
  for (int b = 0; b < 2; b++) {
    const float* rp = b ? refp : preref;
    float rx = rp[(size_t)n * 2 + 0];
    float ry = rp[(size_t)n * 2 + 1];

    int abase = n * 64 + h * 8 + b * 4;
    float a0 = convattn[abase + 0];
    float a1 = convattn[abase + 1];
    float a2 = convattn[abase + 2];
    float a3 = convattn[abase + 3];
    float mx = fmaxf(fmaxf(a0, a1), fmaxf(a2, a3));
    float e0 = expf(a0 - mx), e1 = expf(a1 - mx);
    float e2 = expf(a2 - mx), e3 = expf(a3 - mx);
    float inv = 1.f / (e0 + e1 + e2 + e3);
    float aw[4] = {e0 * inv, e1 * inv, e2 * inv, e3 * inv};

    const float* vb = valp + (size_t)b * NQ * EDIM + h * 32 + d;

#pragma unroll
    for (int p = 0; p < 4; p++) {
      int ob = n * 128 + ((h * 2 + b) * 4 + p) * 2;
      float x = rx * 200.f + convoff[ob + 0] - 0.5f;
      float y = ry * 200.f + convoff[ob + 1] - 0.5f;
      float x0f = floorf(x), y0f = floorf(y);
      float fx = x - x0f, fy = y - y0f;
      int x0 = (int)x0f, y0 = (int)y0f;
      float s = 0.f;
      {
        int xi = x0, yi = y0; float w = (1.f - fx) * (1.f - fy);
        if (xi >= 0 && xi < BEVW && yi >= 0 && yi < BEVH)
          s += w * vb[(size_t)(yi * BEVW + xi) * EDIM];
      }
      {
        int xi = x0 + 1, yi = y0; float w = fx * (1.f - fy);
        if (xi >= 0 && xi < BEVW && yi >= 0 && yi < BEVH)
          s += w * vb[(size_t)(yi * BEVW + xi) * EDIM];
      }
      {
        int xi = x0, yi = y0 + 1; float w = (1.f - fx) * fy;
        if (xi >= 0 && xi < BEVW && yi >= 0 && yi < BEVH)
          s += w * vb[(size_t)(yi * BEVW + xi) * EDIM];
      }
      {
        int xi = x0 + 1, yi = y0 + 1; float w = fx * fy;
        if (xi >= 0 && xi < BEVW && yi >= 0 && yi < BEVH)
          s += w * vb[(size_t)(yi * BEVW + xi) * EDIM];
      }
      acc += aw[p] * s;
    }
  }
  mid[(size_t)n * EDIM + h * 32 + d] = acc * 0.5f;
}

// ---------------------------------------------------------------------------
extern "C" void kernel_launch(void* const* d_in, const int* in_sizes, int n_in,
                              void* d_out, int out_size, void* d_ws, size_t ws_size,
                              hipStream_t stream)
{
  const float* query  = (const float*)d_in[0];
  const float* qpos   = (const float*)d_in[3];
  const float* refp   = (const float*)d_in[4];
  const float* prebev = (const float*)d_in[7];
  const float* preref = (const float*)d_in[8];
  const unsigned char* sos = (const unsigned char*)d_in[9];
  const float* Wv     = (const float*)d_in[10];
  const float* bv     = (const float*)d_in[11];
  const float* Wo     = (const float*)d_in[12];
  const float* bo     = (const float*)d_in[13];
  const float* off_w  = (const float*)d_in[14];
  const float* off_b  = (const float*)d_in[15];
  const float* attn_w = (const float*)d_in[16];
  const float* attn_b = (const float*)d_in[17];
  float* out = (float*)d_out;

  // workspace layout (floats)
  float* q2       = (float*)d_ws;             // 40000*512   = 20,480,000
  float* valp     = q2 + 20480000;            // 80000*256   = 20,480,000
  float* convoff  = valp + 20480000;          // 40000*128   =  5,120,000
  float* convattn = convoff + 5120000;        // 40000*64    =  2,560,000
  float* w_off_r  = convattn + 2560000;       // 128*4608    =    589,824
  float* w_attn_r = w_off_r + 589824;         // 64*4608     =    294,912
  float* mid      = q2;                       // alias: q2 dead after convs

  prep_kernel<<<dim3((NQ * EDIM + 255) / 256), dim3(256), 0, stream>>>(
      query, qpos, prebev, sos, q2);
  reorder_w_kernel<<<dim3((128 * 4608 + 255) / 256), dim3(256), 0, stream>>>(
      off_w, w_off_r, 128);
  reorder_w_kernel<<<dim3((64 * 4608 + 255) / 256), dim3(256), 0, stream>>>(
      attn_w, w_attn_r, 64);

  // valp = val @ Wv^T + bv   (M=80000, N=256, K=256)
  gemm_kernel<SRC_VAL, false><<<dim3(625, 4), dim3(256), 0, stream>>>(
      q2, query, Wv, bv, nullptr, valp, 2 * NQ, 256, 256);

  // conv offsets (M=40000, N=128, K=4608)
  gemm_kernel<SRC_IM2COL, false><<<dim3(313, 2), dim3(256), 0, stream>>>(
      q2, nullptr, w_off_r, off_b, nullptr, convoff, NQ, 128, 4608);

  // conv attn weights (M=40000, N=64, K=4608)
  gemm_kernel<SRC_IM2COL, false><<<dim3(313, 1), dim3(256), 0, stream>>>(
      q2, nullptr, w_attn_r, attn_b, nullptr, convattn, NQ, 64, 4608);

  // softmax + bilinear sampling + queue average -> mid (40000, 256)
  sample_kernel<<<dim3(NQ), dim3(256), 0, stream>>>(
      valp, convoff, convattn, preref, refp, mid);

  // out = mid @ Wo^T + bo + identity   (M=40000, N=256, K=256)
  gemm_kernel<SRC_PLAIN, true><<<dim3(313, 4), dim3(256), 0, stream>>>(
      mid, nullptr, Wo, bo, query, out, NQ, 256, 256);

  (void)in_sizes; (void)n_in; (void)out_size; (void)ws_size;
}

// Round 2
// 890.369 us; speedup vs baseline: 2.3905x; 2.3905x over previous
//
#include <hip/hip_runtime.h>
#include <math.h>

#define NQ    40000
#define EDIM  256
#define H2    512
#define BEVH  200
#define BEVW  200

enum { SRC_VAL = 0, SRC_PLAIN = 2 };

#define BM 128
#define BN 64
#define BK 16

typedef __attribute__((ext_vector_type(8))) short bf16x8;
typedef __attribute__((ext_vector_type(4))) float f32x4;

typedef __attribute__((address_space(3))) unsigned int lds_u32_t;
typedef const __attribute__((address_space(1))) unsigned int g_u32_t;
#define GLOAD_LDS16(g, l) __builtin_amdgcn_global_load_lds((g_u32_t*)(g), (lds_u32_t*)(l), 16, 0, 0)

__device__ __forceinline__ short f2bf(float f) {
  union { float f; unsigned u; } uu; uu.f = f;
  unsigned r = (uu.u + 0x7fff + ((uu.u >> 16) & 1)) >> 16;
  return (short)r;
}

// ---------------------------------------------------------------------------
// pad_kernel: build zero-padded bf16 image img[203][202][512].
// padded row pr maps to image y = pr-1 (so tap ty in {0,1,2} reads row y+ty).
// channel c<256 -> pre (= sos ? query : prebev); c>=256 -> query + qpos.
// ---------------------------------------------------------------------------
__global__ __launch_bounds__(256) void pad_kernel(
    const float* __restrict__ query, const float* __restrict__ qpos,
    const float* __restrict__ prebev, const unsigned char* __restrict__ sos,
    short* __restrict__ img)
{
  const int TOT = 203 * 202 * 64;           // groups of 8 shorts
  int t = blockIdx.x * 256 + threadIdx.x;
  if (t >= TOT) return;
  int s = t * 8;
  int pr = s / (202 * 512);
  int rem = s - pr * (202 * 512);
  int px = rem >> 9;
  int c = rem & 511;
  int y = pr - 1, x = px - 1;

  bf16x8 o;
#pragma unroll
  for (int j = 0; j < 8; j++) o[j] = 0;

  if (y >= 0 && y < BEVH && x >= 0 && x < BEVW) {
    int n = y * BEVW + x;
    if (c < 256) {
      bool sf = sos[0] != 0;
      const float* p = (sf ? query : prebev) + (size_t)n * 256 + c;
      float4 v0 = *(const float4*)p;
      float4 v1 = *(const float4*)(p + 4);
      o[0] = f2bf(v0.x); o[1] = f2bf(v0.y); o[2] = f2bf(v0.z); o[3] = f2bf(v0.w);
      o[4] = f2bf(v1.x); o[5] = f2bf(v1.y); o[6] = f2bf(v1.z); o[7] = f2bf(v1.w);
    } else {
      const float* pq = query + (size_t)n * 256 + (c - 256);
      const float* pp = qpos + (size_t)n * 256 + (c - 256);
      float4 q0 = *(const float4*)pq, q1 = *(const float4*)(pq + 4);
      float4 p0 = *(const float4*)pp, p1 = *(const float4*)(pp + 4);
      o[0] = f2bf(q0.x + p0.x); o[1] = f2bf(q0.y + p0.y);
      o[2] = f2bf(q0.z + p0.z); o[3] = f2bf(q0.w + p0.w);
      o[4] = f2bf(q1.x + p1.x); o[5] = f2bf(q1.y + p1.y);
      o[6] = f2bf(q1.z + p1.z); o[7] = f2bf(q1.w + p1.w);
    }
  }
  *(bf16x8*)&img[s] = o;
}

// ---------------------------------------------------------------------------
// reorder conv weights (co, ci, ky, kx) fp32 -> (co, tap*512+ci) bf16
// ---------------------------------------------------------------------------
__global__ __launch_bounds__(256) void reorder_w_kernel(
    const float* __restrict__ w, short* __restrict__ wr, int CO)
{
  int i = blockIdx.x * 256 + threadIdx.x;
  if (i >= CO * 4608) return;
  int co = i / 4608;
  int r = i - co * 4608;
  int tap = r >> 9;
  int ci = r & 511;
  wr[i] = f2bf(w[(size_t)co * 4608 + ci * 9 + tap]);
}

// ---------------------------------------------------------------------------
// MFMA bf16 im2col conv GEMM.
// C[m][co] = sum_k img2col[m][k] * Wr[co][k] + bias[co],  K = 4608 (tap*512+ci)
// tile: BM=128 x BN=64, BK=64; 256 threads = 4 waves (2x2).
// A staged via global_load_lds (pre-swizzled source, T2 XOR on read).
// ---------------------------------------------------------------------------
__global__ __launch_bounds__(256) void conv_mfma_kernel(
    const short* __restrict__ img,   // padded [203][202][512] bf16
    const short* __restrict__ Wr,    // [CO][4608] bf16 tap-major
    const float* __restrict__ bias,
    float* __restrict__ Cout, int CO)
{
  __shared__ __align__(16) short As[128 * 64];
  __shared__ __align__(16) short Bs[64 * 64];

  const int tid = threadIdx.x;
  const int wv = tid >> 6, lane = tid & 63;
  const int wr_ = wv >> 1, wc = wv & 1;
  const int m0 = blockIdx.x * 128;
  const int n0 = blockIdx.y * 64;

  // swizzled chunk offset (shorts): chunk j=lane&7 holds global chunk j^(row&7),
  // and row&7 == (lane>>3)&7 because every wave-issue covers 8 aligned rows.
  const int csw = ((lane & 7) ^ ((lane >> 3) & 7)) * 8;

  // per-issue A base offsets (shorts): pixel(y,x) of row m; tap offset added per K-tile
  int a_base[4];
#pragma unroll
  for (int i = 0; i < 4; i++) {
    int ml = (i * 4 + wv) * 8 + (lane >> 3);
    int m = m0 + ml;
    int y = m / BEVW;
    int x = m - y * BEVW;
    a_base[i] = (y * 202 + x) * 512 + csw;
  }
  // per-issue B row offsets (shorts)
  int b_base[2];
#pragma unroll
  for (int i = 0; i < 2; i++) {
    int r = n0 + (i * 4 + wv) * 8 + (lane >> 3);
    b_base[i] = r * 4608 + csw;
  }

  f32x4 acc[4][2];
#pragma unroll
  for (int mr = 0; mr < 4; mr++)
#pragma unroll
    for (int nr = 0; nr < 2; nr++) acc[mr][nr] = (f32x4){0.f, 0.f, 0.f, 0.f};

  for (int k0 = 0; k0 < 4608; k0 += 64) {
    int tap = k0 >> 9;
    int c0 = k0 & 511;
    int ty = tap / 3;
    int txp = tap - ty * 3;
    int toff = (ty * 202 + txp) * 512 + c0;

#pragma unroll
    for (int i = 0; i < 4; i++)
      GLOAD_LDS16(img + a_base[i] + toff, &As[(i * 4 + wv) * 512]);
#pragma unroll
    for (int i = 0; i < 2; i++)
      GLOAD_LDS16(Wr + b_base[i] + k0, &Bs[(i * 4 + wv) * 512]);

    __syncthreads();   // drains vmcnt before barrier (compiler-inserted)

#pragma unroll
    for (int ks = 0; ks < 2; ks++) {
      const int kk = ks * 32 + (lane >> 4) * 8;
      bf16x8 af[4], bf[2];
#pragma unroll
      for (int mr = 0; mr < 4; mr++) {
        int row = wr_ * 64 + mr * 16 + (lane & 15);
        af[mr] = *(const bf16x8*)&As[row * 64 + (kk ^ ((row & 7) << 3))];
      }
#pragma unroll
      for (int nr = 0; nr < 2; nr++) {
        int row = wc * 32 + nr * 16 + (lane & 15);
        bf[nr] = *(const bf16x8*)&Bs[row * 64 + (kk ^ ((row & 7) << 3))];
      }
#pragma unroll
      for (int mr = 0; mr < 4; mr++)
#pragma unroll
        for (int nr = 0; nr < 2; nr++)
          acc[mr][nr] = __builtin_amdgcn_mfma_f32_16x16x32_bf16(
              af[mr], bf[nr], acc[mr][nr], 0, 0, 0);
    }
    __syncthreads();   // tile consumed before next overwrite
  }

  // epilogue: C/D layout col=lane&15, row=(lane>>4)*4+reg
#pragma unroll
  for (int mr = 0; mr < 4; mr++) {
#pragma unroll
    for (int nr = 0; nr < 2; nr++) {
      int col = n0 + wc * 32 + nr * 16 + (lane & 15);
      float bsv = bias[col];
#pragma unroll
      for (int r = 0; r < 4; r++) {
        int grow = m0 + wr_ * 64 + mr * 16 + (lane >> 4) * 4 + r;
        if (grow < NQ)
          Cout[(size_t)grow * CO + col] = acc[mr][nr][r] + bsv;
      }
    }
  }
}

// ---------------------------------------------------------------------------
// fp32 tiled GEMM (unchanged structure): C = A[M][K] * B[N][K]^T + bias (+addend)
//   SRC_VAL  : m = b*NQ+n ; b==0 -> (sos? query : prebev)[n], b==1 -> query[n]
//   SRC_PLAIN: A0[m*K + k]
// ---------------------------------------------------------------------------
template <int ASRC, bool ADD_IDENT>
__global__ __launch_bounds__(256) void gemm_kernel(
    const float* __restrict__ A0, const float* __restrict__ A1,
    const unsigned char* __restrict__ Sos,
    const float* __restrict__ B, const float* __restrict__ bias,
    const float* __restrict__ addend, float* __restrict__ C,
    int M, int N, int K)
{
  __shared__ float As[BK][BM];
  __shared__ float Bs[BK][BN];
  int tid = threadIdx.x;
  int m0 = blockIdx.x * BM;
  int n0 = blockIdx.y * BN;
  int tx = tid & 15;
  int ty = tid >> 4;

  bool sf = (ASRC == SRC_VAL) ? (Sos[0] != 0) : false;

  float acc[8][4];
#pragma unroll
  for (int i = 0; i < 8; i++)
#pragma unroll
    for (int j = 0; j < 4; j++) acc[i][j] = 0.f;

  int a_m = tid >> 1;
  int a_k = (tid & 1) * 8;
  int b_n = tid >> 2;
  int b_k = (tid & 3) * 4;

  for (int k0 = 0; k0 < K; k0 += BK) {
    float4 av0 = make_float4(0.f, 0.f, 0.f, 0.f);
    float4 av1 = av0;
    int mg = m0 + a_m;

    if constexpr (ASRC == SRC_VAL) {
      int b = mg >= NQ;
      int n = mg - (b ? NQ : 0);
      const float* base = (b || sf) ? A1 : A0;
      const float* p = base + (size_t)n * EDIM + k0 + a_k;
      av0 = *(const float4*)p;
      av1 = *(const float4*)(p + 4);
    } else {
      if (mg < M) {
        const float* p = A0 + (size_t)mg * K + k0 + a_k;
        av0 = *(const float4*)p;
        av1 = *(const float4*)(p + 4);
      }
    }

    const float* pb = B + (size_t)(n0 + b_n) * K + k0 + b_k;
    float4 bv = *(const float4*)pb;

    __syncthreads();
    As[a_k + 0][a_m] = av0.x;
    As[a_k + 1][a_m] = av0.y;
    As[a_k + 2][a_m] = av0.z;
    As[a_k + 3][a_m] = av0.w;
    As[a_k + 4][a_m] = av1.x;
    As[a_k + 5][a_m] = av1.y;
    As[a_k + 6][a_m] = av1.z;
    As[a_k + 7][a_m] = av1.w;
    Bs[b_k + 0][b_n] = bv.x;
    Bs[b_k + 1][b_n] = bv.y;
    Bs[b_k + 2][b_n] = bv.z;
    Bs[b_k + 3][b_n] = bv.w;
    __syncthreads();

#pragma unroll
    for (int kk = 0; kk < BK; kk++) {
      const float4 Av0 = *(const float4*)&As[kk][ty * 8];
      const float4 Av1 = *(const float4*)&As[kk][ty * 8 + 4];
      const float4 Bv  = *(const float4*)&Bs[kk][tx * 4];
      float a[8] = {Av0.x, Av0.y, Av0.z, Av0.w, Av1.x, Av1.y, Av1.z, Av1.w};
      float bb[4] = {Bv.x, Bv.y, Bv.z, Bv.w};
#pragma unroll
      for (int i = 0; i < 8; i++)
#pragma unroll
        for (int j = 0; j < 4; j++) acc[i][j] = fmaf(a[i], bb[j], acc[i][j]);
    }
  }

  float4 bvec = *(const float4*)&bias[n0 + tx * 4];
#pragma unroll
  for (int i = 0; i < 8; i++) {
    int mg = m0 + ty * 8 + i;
    if (mg < M) {
      float4 o = make_float4(acc[i][0] + bvec.x, acc[i][1] + bvec.y,
                             acc[i][2] + bvec.z, acc[i][3] + bvec.w);
      if constexpr (ADD_IDENT) {
        const float4 ad = *(const float4*)&addend[(size_t)mg * N + n0 + tx * 4];
        o.x += ad.x; o.y += ad.y; o.z += ad.z; o.w += ad.w;
      }
      *(float4*)&C[(size_t)mg * N + n0 + tx * 4] = o;
    }
  }
}

// ---------------------------------------------------------------------------
// sampling: softmax over P per (h,queue), bilinear gather, weighted sum, avg
// ---------------------------------------------------------------------------
__global__ __launch_bounds__(256) void sample_kernel(
    const float* __restrict__ valp, const float* __restrict__ convoff,
    const float* __restrict__ convattn, const float* __restrict__ preref,
    const float* __restrict__ refp, float* __restrict__ mid)
{
  int n = blockIdx.x;
  int tid = threadIdx.x;
  int h = tid >> 5, d = tid & 31;
  float acc = 0.f;

#pragma unroll
  for (int b = 0; b < 2; b++) {
    const float* rp = b ? refp : preref;
    float rx = rp[(size_t)n * 2 + 0];
    float ry = rp[(size_t)n * 2 + 1];

    int abase = n * 64 + h * 8 + b * 4;
    float a0 = convattn[abase + 0];
    float a1 = convattn[abase + 1];
    float a2 = convattn[abase + 2];
    float a3 = convattn[abase + 3];
    float mx = fmaxf(fmaxf(a0, a1), fmaxf(a2, a3));
    float e0 = expf(a0 - mx), e1 = expf(a1 - mx);
    float e2 = expf(a2 - mx), e3 = expf(a3 - mx);
    float inv = 1.f / (e0 + e1 + e2 + e3);
    float aw[4] = {e0 * inv, e1 * inv, e2 * inv, e3 * inv};

    const float* vb = valp + (size_t)b * NQ * EDIM + h * 32 + d;

#pragma unroll
    for (int p = 0; p < 4; p++) {
      int ob = n * 128 + ((h * 2 + b) * 4 + p) * 2;
      float x = rx * 200.f + convoff[ob + 0] - 0.5f;
      float y = ry * 200.f + convoff[ob + 1] - 0.5f;
      float x0f = floorf(x), y0f = floorf(y);
      float fx = x - x0f, fy = y - y0f;
      int x0 = (int)x0f, y0 = (int)y0f;
      float s = 0.f;
      {
        int xi = x0, yi = y0; float w = (1.f - fx) * (1.f - fy);
        if (xi >= 0 && xi < BEVW && yi >= 0 && yi < BEVH)
          s += w * vb[(size_t)(yi * BEVW + xi) * EDIM];
      }
      {
        int xi = x0 + 1, yi = y0; float w = fx * (1.f - fy);
        if (xi >= 0 && xi < BEVW && yi >= 0 && yi < BEVH)
          s += w * vb[(size_t)(yi * BEVW + xi) * EDIM];
      }
      {
        int xi = x0, yi = y0 + 1; float w = (1.f - fx) * fy;
        if (xi >= 0 && xi < BEVW && yi >= 0 && yi < BEVH)
          s += w * vb[(size_t)(yi * BEVW + xi) * EDIM];
      }
      {
        int xi = x0 + 1, yi = y0 + 1; float w = fx * fy;
        if (xi >= 0 && xi < BEVW && yi >= 0 && yi < BEVH)
          s += w * vb[(size_t)(yi * BEVW + xi) * EDIM];
      }
      acc += aw[p] * s;
    }
  }
  mid[(size_t)n * EDIM + h * 32 + d] = acc * 0.5f;
}

// ---------------------------------------------------------------------------
extern "C" void kernel_launch(void* const* d_in, const int* in_sizes, int n_in,
                              void* d_out, int out_size, void* d_ws, size_t ws_size,
                              hipStream_t stream)
{
  const float* query  = (const float*)d_in[0];
  const float* qpos   = (const float*)d_in[3];
  const float* refp   = (const float*)d_in[4];
  const float* prebev = (const float*)d_in[7];
  const float* preref = (const float*)d_in[8];
  const unsigned char* sos = (const unsigned char*)d_in[9];
  const float* Wv     = (const float*)d_in[10];
  const float* bv     = (const float*)d_in[11];
  const float* Wo     = (const float*)d_in[12];
  const float* bo     = (const float*)d_in[13];
  const float* off_w  = (const float*)d_in[14];
  const float* off_b  = (const float*)d_in[15];
  const float* attn_w = (const float*)d_in[16];
  const float* attn_b = (const float*)d_in[17];
  float* out = (float*)d_out;

  // workspace layout
  float* valp     = (float*)d_ws;             // 80000*256  = 20,480,000 f
  float* convoff  = valp + 20480000;          // 40000*128  =  5,120,000 f
  float* convattn = convoff + 5120000;        // 40000*64   =  2,560,000 f
  float* mid      = convattn + 2560000;       // 40000*256  = 10,240,000 f
  short* img      = (short*)(mid + 10240000); // 203*202*512 = 20,996,672 s
  short* wro      = img + 21000192;           // 128*4608   =    589,824 s
  short* wra      = wro + 589824;             // 64*4608    =    294,912 s

  pad_kernel<<<dim3((203 * 202 * 64 + 255) / 256), dim3(256), 0, stream>>>(
      query, qpos, prebev, sos, img);
  reorder_w_kernel<<<dim3((128 * 4608 + 255) / 256), dim3(256), 0, stream>>>(
      off_w, wro, 128);
  reorder_w_kernel<<<dim3((64 * 4608 + 255) / 256), dim3(256), 0, stream>>>(
      attn_w, wra, 64);

  // valp = val @ Wv^T + bv   (M=80000, N=256, K=256) fp32
  gemm_kernel<SRC_VAL, false><<<dim3(625, 4), dim3(256), 0, stream>>>(
      prebev, query, sos, Wv, bv, nullptr, valp, 2 * NQ, 256, 256);

  // conv offsets (M=40000, N=128, K=4608) bf16 MFMA
  conv_mfma_kernel<<<dim3(313, 2), dim3(256), 0, stream>>>(
      img, wro, off_b, convoff, 128);

  // conv attn weights (M=40000, N=64, K=4608) bf16 MFMA
  conv_mfma_kernel<<<dim3(313, 1), dim3(256), 0, stream>>>(
      img, wra, attn_b, convattn, 64);

  // softmax + bilinear sampling + queue average -> mid
  sample_kernel<<<dim3(NQ), dim3(256), 0, stream>>>(
      valp, convoff, convattn, preref, refp, mid);

  // out = mid @ Wo^T + bo + identity   (M=40000, N=256, K=256) fp32
  gemm_kernel<SRC_PLAIN, true><<<dim3(313, 4), dim3(256), 0, stream>>>(
      mid, nullptr, nullptr, Wo, bo, query, out, NQ, 256, 256);

  (void)in_sizes; (void)n_in; (void)out_size; (void)ws_size;
}

// Round 3
// 587.518 us; speedup vs baseline: 3.6228x; 1.5155x over previous
//
#include <hip/hip_runtime.h>
#include <math.h>

#define NQ    40000
#define EDIM  256
#define BEVH  200
#define BEVW  200

enum { A_IM2COL = 0, A_VAL = 1, A_PLAIN = 2 };

typedef __attribute__((ext_vector_type(8))) short bf16x8;
typedef __attribute__((ext_vector_type(4))) short bf16x4;
typedef __attribute__((ext_vector_type(4))) float f32x4;

typedef __attribute__((address_space(3))) unsigned int lds_u32_t;
typedef const __attribute__((address_space(1))) unsigned int g_u32_t;
#define GLOAD_LDS16(g, l) __builtin_amdgcn_global_load_lds((g_u32_t*)(g), (lds_u32_t*)(l), 16, 0, 0)

__device__ __forceinline__ short f2bf(float f) {
  union { float f; unsigned u; } uu; uu.f = f;
  unsigned r = (uu.u + 0x7fff + ((uu.u >> 16) & 1)) >> 16;
  return (short)r;
}
__device__ __forceinline__ float bf2f(short s) {
  union { unsigned u; float f; } v;
  v.u = ((unsigned)(unsigned short)s) << 16;
  return v.f;
}

// ---------------------------------------------------------------------------
// pad_kernel: zero-padded bf16 image img[203][202][512]; image (y,x) lives at
// padded (y+1, x+1). c<256 -> pre (= sos ? query : prebev); c>=256 -> q+qpos.
// Also writes qbf[n][0:256] = bf16(query) (for the val-GEMM second half).
// ---------------------------------------------------------------------------
__global__ __launch_bounds__(256) void pad_kernel(
    const float* __restrict__ query, const float* __restrict__ qpos,
    const float* __restrict__ prebev, const unsigned char* __restrict__ sos,
    short* __restrict__ img, short* __restrict__ qbf)
{
  const int TOT = 203 * 202 * 64;           // groups of 8 shorts
  int t = blockIdx.x * 256 + threadIdx.x;
  if (t >= TOT) return;
  int s = t * 8;
  int pr = s / (202 * 512);
  int rem = s - pr * (202 * 512);
  int px = rem >> 9;
  int c = rem & 511;
  int y = pr - 1, x = px - 1;

  bf16x8 o;
#pragma unroll
  for (int j = 0; j < 8; j++) o[j] = 0;

  if (y >= 0 && y < BEVH && x >= 0 && x < BEVW) {
    int n = y * BEVW + x;
    if (c < 256) {
      bool sf = sos[0] != 0;
      const float* p = (sf ? query : prebev) + (size_t)n * 256 + c;
      float4 v0 = *(const float4*)p;
      float4 v1 = *(const float4*)(p + 4);
      o[0] = f2bf(v0.x); o[1] = f2bf(v0.y); o[2] = f2bf(v0.z); o[3] = f2bf(v0.w);
      o[4] = f2bf(v1.x); o[5] = f2bf(v1.y); o[6] = f2bf(v1.z); o[7] = f2bf(v1.w);
    } else {
      const float* pq = query + (size_t)n * 256 + (c - 256);
      const float* pp = qpos + (size_t)n * 256 + (c - 256);
      float4 q0 = *(const float4*)pq, q1 = *(const float4*)(pq + 4);
      float4 p0 = *(const float4*)pp, p1 = *(const float4*)(pp + 4);
      bf16x8 qo;
      qo[0] = f2bf(q0.x); qo[1] = f2bf(q0.y); qo[2] = f2bf(q0.z); qo[3] = f2bf(q0.w);
      qo[4] = f2bf(q1.x); qo[5] = f2bf(q1.y); qo[6] = f2bf(q1.z); qo[7] = f2bf(q1.w);
      *(bf16x8*)&qbf[(size_t)n * 256 + (c - 256)] = qo;
      o[0] = f2bf(q0.x + p0.x); o[1] = f2bf(q0.y + p0.y);
      o[2] = f2bf(q0.z + p0.z); o[3] = f2bf(q0.w + p0.w);
      o[4] = f2bf(q1.x + p1.x); o[5] = f2bf(q1.y + p1.y);
      o[6] = f2bf(q1.z + p1.z); o[7] = f2bf(q1.w + p1.w);
    }
  }
  *(bf16x8*)&img[s] = o;
}

// ---------------------------------------------------------------------------
// conv weights (co,ci,ky,kx) fp32 -> concat [192][tap*512+ci] bf16 + bias cat
// ---------------------------------------------------------------------------
__global__ __launch_bounds__(256) void reorder_cat_kernel(
    const float* __restrict__ off_w, const float* __restrict__ off_b,
    const float* __restrict__ attn_w, const float* __restrict__ attn_b,
    short* __restrict__ wcat, float* __restrict__ bcat)
{
  int i = blockIdx.x * 256 + threadIdx.x;
  if (i < 192) bcat[i] = i < 128 ? off_b[i] : attn_b[i - 128];
  if (i >= 192 * 4608) return;
  int co = i / 4608;
  int r = i - co * 4608;
  int tap = r >> 9, ci = r & 511;
  float v = co < 128 ? off_w[(size_t)co * 4608 + ci * 9 + tap]
                     : attn_w[(size_t)(co - 128) * 4608 + ci * 9 + tap];
  wcat[i] = f2bf(v);
}

// cast Wv, Wo (256x256 each, [co][k] row-major already) to bf16
__global__ __launch_bounds__(256) void wcast_kernel(
    const float* __restrict__ Wv, const float* __restrict__ Wo,
    short* __restrict__ wvb, short* __restrict__ wob)
{
  int t = blockIdx.x * 256 + threadIdx.x;
  if (t >= 16384) return;
  const float* src = t < 8192 ? Wv + (size_t)t * 8 : Wo + (size_t)(t - 8192) * 8;
  short* dst = t < 8192 ? wvb + (size_t)t * 8 : wob + (size_t)(t - 8192) * 8;
  float4 v0 = *(const float4*)src, v1 = *(const float4*)(src + 4);
  bf16x8 o;
  o[0] = f2bf(v0.x); o[1] = f2bf(v0.y); o[2] = f2bf(v0.z); o[3] = f2bf(v0.w);
  o[4] = f2bf(v1.x); o[5] = f2bf(v1.y); o[6] = f2bf(v1.z); o[7] = f2bf(v1.w);
  *(bf16x8*)dst = o;
}

// ---------------------------------------------------------------------------
// Unified bf16 MFMA GEMM: C[m][co] = sum_k A[m][k]*B[co][k] + bias[co]
// tile BM=128 x BN=64, BK=64; 256 threads = 4 waves (2x2).
// A via global_load_lds, pre-swizzled source (chunk XOR), swizzled ds_read.
// AMODE: IM2COL (K=4608, padded img taps) | VAL (K=256, img center / qbf) |
//        PLAIN (K=256, bf16 row-major)
// ---------------------------------------------------------------------------
template <int AMODE, int KTOT, bool ADD_IDENT, bool OUT_BF16>
__global__ __launch_bounds__(256) void mfma_gemm_kernel(
    const short* __restrict__ A0, const short* __restrict__ A1,
    const short* __restrict__ Bw, const float* __restrict__ bias,
    const float* __restrict__ addend,
    float* __restrict__ Cf, short* __restrict__ Cb,
    int M, int CO)
{
  __shared__ __align__(16) short As[128 * 64];
  __shared__ __align__(16) short Bs[64 * 64];

  const int tid = threadIdx.x;
  const int wv = tid >> 6, lane = tid & 63;
  const int wr_ = wv >> 1, wc = wv & 1;
  const int m0 = blockIdx.x * 128;
  const int n0 = blockIdx.y * 64;

  // swizzle: LDS chunk j of row r holds global chunk j ^ (r & 7)
  const int csw = ((lane & 7) ^ ((lane >> 3) & 7)) * 8;

  const short* ap[4];
#pragma unroll
  for (int i = 0; i < 4; i++) {
    int m = m0 + (i * 4 + wv) * 8 + (lane >> 3);
    if constexpr (AMODE == A_IM2COL) {
      int y = m / BEVW;
      int x = m - y * BEVW;
      ap[i] = A0 + ((size_t)y * 202 + x) * 512 + csw;  // + tap offset per K-tile
    } else if constexpr (AMODE == A_VAL) {
      if (m < NQ) {
        int y = m / BEVW;
        int x = m - y * BEVW;
        ap[i] = A0 + ((size_t)(y + 1) * 202 + (x + 1)) * 512 + csw;
      } else {
        ap[i] = A1 + (size_t)(m - NQ) * 256 + csw;
      }
    } else {
      int mc = m < M ? m : M - 1;
      ap[i] = A0 + (size_t)mc * KTOT + csw;
    }
  }
  const short* bp[2];
#pragma unroll
  for (int i = 0; i < 2; i++) {
    int r = n0 + (i * 4 + wv) * 8 + (lane >> 3);
    bp[i] = Bw + (size_t)r * KTOT + csw;
  }

  f32x4 acc[4][2];
#pragma unroll
  for (int mr = 0; mr < 4; mr++)
#pragma unroll
    for (int nr = 0; nr < 2; nr++) acc[mr][nr] = (f32x4){0.f, 0.f, 0.f, 0.f};

  for (int k0 = 0; k0 < KTOT; k0 += 64) {
    int koff;
    if constexpr (AMODE == A_IM2COL) {
      int tap = k0 >> 9, c0 = k0 & 511;
      int ty = tap / 3, txp = tap - ty * 3;
      koff = (ty * 202 + txp) * 512 + c0;
    } else {
      koff = k0;
    }

#pragma unroll
    for (int i = 0; i < 4; i++)
      GLOAD_LDS16(ap[i] + koff, &As[(i * 4 + wv) * 512]);
#pragma unroll
    for (int i = 0; i < 2; i++)
      GLOAD_LDS16(bp[i] + k0, &Bs[(i * 4 + wv) * 512]);

    __syncthreads();

#pragma unroll
    for (int ks = 0; ks < 2; ks++) {
      const int kk = ks * 32 + (lane >> 4) * 8;
      bf16x8 af[4], bfr[2];
#pragma unroll
      for (int mr = 0; mr < 4; mr++) {
        int row = wr_ * 64 + mr * 16 + (lane & 15);
        af[mr] = *(const bf16x8*)&As[row * 64 + (kk ^ ((row & 7) << 3))];
      }
#pragma unroll
      for (int nr = 0; nr < 2; nr++) {
        int row = wc * 32 + nr * 16 + (lane & 15);
        bfr[nr] = *(const bf16x8*)&Bs[row * 64 + (kk ^ ((row & 7) << 3))];
      }
#pragma unroll
      for (int mr = 0; mr < 4; mr++)
#pragma unroll
        for (int nr = 0; nr < 2; nr++)
          acc[mr][nr] = __builtin_amdgcn_mfma_f32_16x16x32_bf16(
              af[mr], bfr[nr], acc[mr][nr], 0, 0, 0);
    }
    __syncthreads();
  }

  // epilogue: C/D layout col=lane&15, row=(lane>>4)*4+reg
#pragma unroll
  for (int mr = 0; mr < 4; mr++) {
#pragma unroll
    for (int nr = 0; nr < 2; nr++) {
      int col = n0 + wc * 32 + nr * 16 + (lane & 15);
      float bsv = bias[col];
#pragma unroll
      for (int r = 0; r < 4; r++) {
        int grow = m0 + wr_ * 64 + mr * 16 + (lane >> 4) * 4 + r;
        if (grow < M) {
          float o = acc[mr][nr][r] + bsv;
          if constexpr (ADD_IDENT) o += addend[(size_t)grow * CO + col];
          if constexpr (OUT_BF16) Cb[(size_t)grow * CO + col] = f2bf(o);
          else                    Cf[(size_t)grow * CO + col] = o;
        }
      }
    }
  }
}

// ---------------------------------------------------------------------------
// sample v2: 1 wave per query n; lane = h*8+g, g = d-quad index (d=g*4..g*4+3)
// softmax over P per (h,queue); bilinear gather from bf16 valp; writes bf16 mid
// convall: [n][192], cols 0..127 = offsets, 128..191 = attn logits
// ---------------------------------------------------------------------------
__global__ __launch_bounds__(256) void sample_kernel(
    const short* __restrict__ valpb, const float* __restrict__ convall,
    const float* __restrict__ preref, const float* __restrict__ refp,
    short* __restrict__ midb)
{
  int wv = threadIdx.x >> 6;
  int n = blockIdx.x * 4 + wv;
  int lane = threadIdx.x & 63;
  int h = lane >> 3, g = lane & 7;

  const float* ca = convall + (size_t)n * 192;
  f32x4 acc = (f32x4){0.f, 0.f, 0.f, 0.f};

#pragma unroll
  for (int b = 0; b < 2; b++) {
    const float* rp = b ? refp : preref;
    float rx = rp[(size_t)n * 2 + 0] * 200.f - 0.5f;
    float ry = rp[(size_t)n * 2 + 1] * 200.f - 0.5f;

    float4 a = *(const float4*)(ca + 128 + h * 8 + b * 4);
    float mx = fmaxf(fmaxf(a.x, a.y), fmaxf(a.z, a.w));
    float e0 = __expf(a.x - mx), e1 = __expf(a.y - mx);
    float e2 = __expf(a.z - mx), e3 = __expf(a.w - mx);
    float inv = 1.f / (e0 + e1 + e2 + e3);
    float aw[4] = {e0 * inv, e1 * inv, e2 * inv, e3 * inv};

    float4 o01 = *(const float4*)(ca + (h * 2 + b) * 8);
    float4 o23 = *(const float4*)(ca + (h * 2 + b) * 8 + 4);
    float ox[4] = {o01.x, o01.z, o23.x, o23.z};
    float oy[4] = {o01.y, o01.w, o23.y, o23.w};

    const short* vb = valpb + (size_t)b * NQ * EDIM + h * 32 + g * 4;

#pragma unroll
    for (int p = 0; p < 4; p++) {
      float x = rx + ox[p];
      float y = ry + oy[p];
      float x0f = floorf(x), y0f = floorf(y);
      float fx = x - x0f, fy = y - y0f;
      int x0 = (int)x0f, y0 = (int)y0f;
      float wt[4] = {(1.f - fx) * (1.f - fy), fx * (1.f - fy),
                     (1.f - fx) * fy, fx * fy};
      int xs[4] = {x0, x0 + 1, x0, x0 + 1};
      int ys[4] = {y0, y0, y0 + 1, y0 + 1};
#pragma unroll
      for (int c = 0; c < 4; c++) {
        if (xs[c] >= 0 && xs[c] < BEVW && ys[c] >= 0 && ys[c] < BEVH) {
          bf16x4 v = *(const bf16x4*)&vb[(size_t)(ys[c] * BEVW + xs[c]) * EDIM];
          float cw = aw[p] * wt[c];
          acc[0] += cw * bf2f(v[0]);
          acc[1] += cw * bf2f(v[1]);
          acc[2] += cw * bf2f(v[2]);
          acc[3] += cw * bf2f(v[3]);
        }
      }
    }
  }

  bf16x4 m4;
#pragma unroll
  for (int j = 0; j < 4; j++) m4[j] = f2bf(acc[j] * 0.5f);
  *(bf16x4*)&midb[(size_t)n * 256 + h * 32 + g * 4] = m4;
}

// ---------------------------------------------------------------------------
extern "C" void kernel_launch(void* const* d_in, const int* in_sizes, int n_in,
                              void* d_out, int out_size, void* d_ws, size_t ws_size,
                              hipStream_t stream)
{
  const float* query  = (const float*)d_in[0];
  const float* qpos   = (const float*)d_in[3];
  const float* refp   = (const float*)d_in[4];
  const float* prebev = (const float*)d_in[7];
  const float* preref = (const float*)d_in[8];
  const unsigned char* sos = (const unsigned char*)d_in[9];
  const float* Wv     = (const float*)d_in[10];
  const float* bv     = (const float*)d_in[11];
  const float* Wo     = (const float*)d_in[12];
  const float* bo     = (const float*)d_in[13];
  const float* off_w  = (const float*)d_in[14];
  const float* off_b  = (const float*)d_in[15];
  const float* attn_w = (const float*)d_in[16];
  const float* attn_b = (const float*)d_in[17];
  float* out = (float*)d_out;

  // workspace layout
  float* convall = (float*)d_ws;                    // 40000*192 = 7,680,000 f
  short* valpb  = (short*)(convall + 7680000);      // 80000*256 = 20,480,000 s
  short* img    = valpb + 20480000;                 // 203*202*512 = 20,996,672 s
  short* qbf    = img + 20996672;                   // 40000*256 = 10,240,000 s
  short* midb   = qbf + 10240000;                   // 40000*256 = 10,240,000 s
  short* wcat   = midb + 10240000;                  // 192*4608 = 884,736 s
  short* wvb    = wcat + 884736;                    // 65,536 s
  short* wob    = wvb + 65536;                      // 65,536 s
  float* bcat   = (float*)(wob + 65536);            // 192 f

  pad_kernel<<<dim3((203 * 202 * 64 + 255) / 256), dim3(256), 0, stream>>>(
      query, qpos, prebev, sos, img, qbf);
  reorder_cat_kernel<<<dim3((192 * 4608 + 255) / 256), dim3(256), 0, stream>>>(
      off_w, off_b, attn_w, attn_b, wcat, bcat);
  wcast_kernel<<<dim3(64), dim3(256), 0, stream>>>(Wv, Wo, wvb, wob);

  // valp(bf16) = val @ Wv^T + bv   (M=80000, N=256, K=256)
  mfma_gemm_kernel<A_VAL, 256, false, true><<<dim3(625, 4), dim3(256), 0, stream>>>(
      img, qbf, wvb, bv, nullptr, nullptr, valpb, 2 * NQ, 256);

  // merged convs (M=40000, N=192, K=4608) -> convall fp32
  mfma_gemm_kernel<A_IM2COL, 4608, false, false><<<dim3(313, 3), dim3(256), 0, stream>>>(
      img, nullptr, wcat, bcat, nullptr, convall, nullptr, NQ, 192);

  // softmax + bilinear sampling + queue average -> midb bf16
  sample_kernel<<<dim3(10000), dim3(256), 0, stream>>>(
      valpb, convall, preref, refp, midb);

  // out = mid @ Wo^T + bo + identity   (M=40000, N=256, K=256) -> fp32
  mfma_gemm_kernel<A_PLAIN, 256, true, false><<<dim3(313, 4), dim3(256), 0, stream>>>(
      midb, nullptr, wob, bo, query, out, nullptr, NQ, 256);

  (void)in_sizes; (void)n_in; (void)out_size; (void)ws_size;
}

// Round 6
// 460.697 us; speedup vs baseline: 4.6200x; 1.2753x over previous
//
#include <hip/hip_runtime.h>
#include <math.h>

#define NQ    40000
#define EDIM  256
#define BEVH  200
#define BEVW  200

enum { A_IM2COL = 0, A_VAL = 1, A_PLAIN = 2 };
enum { OUT_F32 = 0, OUT_VSLAB = 1, OUT_CONV = 2, OUT_F32ADD = 3 };

typedef __attribute__((ext_vector_type(8))) short bf16x8;
typedef __attribute__((ext_vector_type(4))) short bf16x4;
typedef __attribute__((ext_vector_type(4))) float f32x4;

typedef __attribute__((address_space(3))) unsigned int lds_u32_t;
typedef const __attribute__((address_space(1))) unsigned int g_u32_t;
#define GLOAD_LDS16(g, l) __builtin_amdgcn_global_load_lds((g_u32_t*)(g), (lds_u32_t*)(l), 16, 0, 0)

__device__ __forceinline__ short f2bf(float f) {
  union { float f; unsigned u; } uu; uu.f = f;
  unsigned r = (uu.u + 0x7fff + ((uu.u >> 16) & 1)) >> 16;
  return (short)r;
}
__device__ __forceinline__ float bf2f(short s) {
  union { unsigned u; float f; } v;
  v.u = ((unsigned)(unsigned short)s) << 16;
  return v.f;
}

// ---------------------------------------------------------------------------
// pad_kernel: zero-padded bf16 image img[203][202][512]; image (y,x) at padded
// (y+1,x+1). c<256 -> pre (= sos ? query : prebev); c>=256 -> query+qpos.
// Also writes qbf[n][0:256] = bf16(query).
// ---------------------------------------------------------------------------
__global__ __launch_bounds__(256) void pad_kernel(
    const float* __restrict__ query, const float* __restrict__ qpos,
    const float* __restrict__ prebev, const unsigned char* __restrict__ sos,
    short* __restrict__ img, short* __restrict__ qbf)
{
  const int TOT = 203 * 202 * 64;
  int t = blockIdx.x * 256 + threadIdx.x;
  if (t >= TOT) return;
  int s = t * 8;
  int pr = s / (202 * 512);
  int rem = s - pr * (202 * 512);
  int px = rem >> 9;
  int c = rem & 511;
  int y = pr - 1, x = px - 1;

  bf16x8 o;
#pragma unroll
  for (int j = 0; j < 8; j++) o[j] = 0;

  if (y >= 0 && y < BEVH && x >= 0 && x < BEVW) {
    int n = y * BEVW + x;
    if (c < 256) {
      bool sf = sos[0] != 0;
      const float* p = (sf ? query : prebev) + (size_t)n * 256 + c;
      float4 v0 = *(const float4*)p;
      float4 v1 = *(const float4*)(p + 4);
      o[0] = f2bf(v0.x); o[1] = f2bf(v0.y); o[2] = f2bf(v0.z); o[3] = f2bf(v0.w);
      o[4] = f2bf(v1.x); o[5] = f2bf(v1.y); o[6] = f2bf(v1.z); o[7] = f2bf(v1.w);
    } else {
      const float* pq = query + (size_t)n * 256 + (c - 256);
      const float* pp = qpos + (size_t)n * 256 + (c - 256);
      float4 q0 = *(const float4*)pq, q1 = *(const float4*)(pq + 4);
      float4 p0 = *(const float4*)pp, p1 = *(const float4*)(pp + 4);
      bf16x8 qo;
      qo[0] = f2bf(q0.x); qo[1] = f2bf(q0.y); qo[2] = f2bf(q0.z); qo[3] = f2bf(q0.w);
      qo[4] = f2bf(q1.x); qo[5] = f2bf(q1.y); qo[6] = f2bf(q1.z); qo[7] = f2bf(q1.w);
      *(bf16x8*)&qbf[(size_t)n * 256 + (c - 256)] = qo;
      o[0] = f2bf(q0.x + p0.x); o[1] = f2bf(q0.y + p0.y);
      o[2] = f2bf(q0.z + p0.z); o[3] = f2bf(q0.w + p0.w);
      o[4] = f2bf(q1.x + p1.x); o[5] = f2bf(q1.y + p1.y);
      o[6] = f2bf(q1.z + p1.z); o[7] = f2bf(q1.w + p1.w);
    }
  }
  *(bf16x8*)&img[s] = o;
}

// ---------------------------------------------------------------------------
// conv weights (co,ci,ky,kx) fp32 -> concat [192][tap*512+ci] bf16 + bias cat
// ---------------------------------------------------------------------------
__global__ __launch_bounds__(256) void reorder_cat_kernel(
    const float* __restrict__ off_w, const float* __restrict__ off_b,
    const float* __restrict__ attn_w, const float* __restrict__ attn_b,
    short* __restrict__ wcat, float* __restrict__ bcat)
{
  int i = blockIdx.x * 256 + threadIdx.x;
  if (i < 192) bcat[i] = i < 128 ? off_b[i] : attn_b[i - 128];
  if (i >= 192 * 4608) return;
  int co = i / 4608;
  int r = i - co * 4608;
  int tap = r >> 9, ci = r & 511;
  float v = co < 128 ? off_w[(size_t)co * 4608 + ci * 9 + tap]
                     : attn_w[(size_t)(co - 128) * 4608 + ci * 9 + tap];
  wcat[i] = f2bf(v);
}

__global__ __launch_bounds__(256) void wcast_kernel(
    const float* __restrict__ Wv, const float* __restrict__ Wo,
    short* __restrict__ wvb, short* __restrict__ wob)
{
  int t = blockIdx.x * 256 + threadIdx.x;
  if (t >= 16384) return;
  const float* src = t < 8192 ? Wv + (size_t)t * 8 : Wo + (size_t)(t - 8192) * 8;
  short* dst = t < 8192 ? wvb + (size_t)t * 8 : wob + (size_t)(t - 8192) * 8;
  float4 v0 = *(const float4*)src, v1 = *(const float4*)(src + 4);
  bf16x8 o;
  o[0] = f2bf(v0.x); o[1] = f2bf(v0.y); o[2] = f2bf(v0.z); o[3] = f2bf(v0.w);
  o[4] = f2bf(v1.x); o[5] = f2bf(v1.y); o[6] = f2bf(v1.z); o[7] = f2bf(v1.w);
  *(bf16x8*)dst = o;
}

// ---------------------------------------------------------------------------
// Unified bf16 MFMA GEMM: C[m][co] = sum_k A[m][k]*B[co][k] + bias[co]
// TBM x TBN tile, BK=64; 256 threads = 4 waves (2x2); wave tile TBM/2 x TBN/2.
// A/B staged via global_load_lds (pre-swizzled source, XOR'd ds_read).
// OUTMODE: VSLAB -> valpb[(h*2+b)][n][32] bf16 ; CONV -> convall[h][n][24] f32 ;
//          F32ADD -> Cf[m][256] = o + addend
// ---------------------------------------------------------------------------
template <int AMODE, int KTOT, int TBM, int TBN, int OUTMODE>
__global__ __launch_bounds__(256) void mfma_gemm_kernel(
    const short* __restrict__ A0, const short* __restrict__ A1,
    const short* __restrict__ Bw, const float* __restrict__ bias,
    const float* __restrict__ addend,
    float* __restrict__ Cf, short* __restrict__ Cb, int M)
{
  constexpr int A_ISS = TBM / 32;
  constexpr int B_ISS = TBN / 32;
  constexpr int MR = TBM / 32;     // frags per wave in M (wave M = TBM/2)
  constexpr int NR = TBN / 32;

  __shared__ __align__(16) short As[TBM * 64];
  __shared__ __align__(16) short Bs[TBN * 64];

  const int tid = threadIdx.x;
  const int wv = tid >> 6, lane = tid & 63;
  const int wr_ = wv >> 1, wc = wv & 1;

  int bx = blockIdx.x;
  if constexpr (AMODE == A_IM2COL) {
    // bijective XCD-chunk swizzle for grid 625 (q=78, r=1): vertical-neighbor
    // strips share image rows -> keep them on the same XCD's L2.
    int xcd = bx & 7, pos = bx >> 3;
    bx = (xcd < 1 ? xcd * 79 : 79 + (xcd - 1) * 78) + pos;
  }
  const int m0 = bx * TBM;
  const int n0 = blockIdx.y * TBN;

  // swizzle: LDS chunk j of row r holds global chunk j ^ (r & 7)
  const int csw = ((lane & 7) ^ ((lane >> 3) & 7)) * 8;

  const short* ap[A_ISS];
#pragma unroll
  for (int i = 0; i < A_ISS; i++) {
    int m = m0 + (i * 4 + wv) * 8 + (lane >> 3);
    if constexpr (AMODE == A_IM2COL) {
      int y = m / BEVW;
      int x = m - y * BEVW;
      ap[i] = A0 + ((size_t)y * 202 + x) * 512 + csw;   // + tap offset per K-tile
    } else if constexpr (AMODE == A_VAL) {
      if (m < NQ) {
        int y = m / BEVW;
        int x = m - y * BEVW;
        ap[i] = A0 + ((size_t)(y + 1) * 202 + (x + 1)) * 512 + csw;
      } else {
        ap[i] = A1 + (size_t)(m - NQ) * 256 + csw;
      }
    } else {
      int mc = m < M ? m : M - 1;
      ap[i] = A0 + (size_t)mc * KTOT + csw;
    }
  }
  const short* bp[B_ISS];
#pragma unroll
  for (int i = 0; i < B_ISS; i++) {
    int r = n0 + (i * 4 + wv) * 8 + (lane >> 3);
    bp[i] = Bw + (size_t)r * KTOT + csw;
  }

  f32x4 acc[MR][NR];
#pragma unroll
  for (int mr = 0; mr < MR; mr++)
#pragma unroll
    for (int nr = 0; nr < NR; nr++) acc[mr][nr] = (f32x4){0.f, 0.f, 0.f, 0.f};

  for (int k0 = 0; k0 < KTOT; k0 += 64) {
    int koff;
    if constexpr (AMODE == A_IM2COL) {
      int tap = k0 >> 9, c0 = k0 & 511;
      int ty = tap / 3, txp = tap - ty * 3;
      koff = (ty * 202 + txp) * 512 + c0;
    } else {
      koff = k0;
    }

#pragma unroll
    for (int i = 0; i < A_ISS; i++)
      GLOAD_LDS16(ap[i] + koff, &As[(i * 4 + wv) * 512]);
#pragma unroll
    for (int i = 0; i < B_ISS; i++)
      GLOAD_LDS16(bp[i] + k0, &Bs[(i * 4 + wv) * 512]);

    __syncthreads();

#pragma unroll
    for (int ks = 0; ks < 2; ks++) {
      const int kk = ks * 32 + (lane >> 4) * 8;
      bf16x8 af[MR], bfr[NR];
#pragma unroll
      for (int mr = 0; mr < MR; mr++) {
        int row = wr_ * (TBM / 2) + mr * 16 + (lane & 15);
        af[mr] = *(const bf16x8*)&As[row * 64 + (kk ^ ((row & 7) << 3))];
      }
#pragma unroll
      for (int nr = 0; nr < NR; nr++) {
        int row = wc * (TBN / 2) + nr * 16 + (lane & 15);
        bfr[nr] = *(const bf16x8*)&Bs[row * 64 + (kk ^ ((row & 7) << 3))];
      }
#pragma unroll
      for (int mr = 0; mr < MR; mr++)
#pragma unroll
        for (int nr = 0; nr < NR; nr++)
          acc[mr][nr] = __builtin_amdgcn_mfma_f32_16x16x32_bf16(
              af[mr], bfr[nr], acc[mr][nr], 0, 0, 0);
    }
    __syncthreads();
  }

  // epilogue: C/D layout col=lane&15, row=(lane>>4)*4+reg
#pragma unroll
  for (int mr = 0; mr < MR; mr++) {
#pragma unroll
    for (int nr = 0; nr < NR; nr++) {
      int col = n0 + wc * (TBN / 2) + nr * 16 + (lane & 15);
      float bsv = bias[col];
#pragma unroll
      for (int r = 0; r < 4; r++) {
        int grow = m0 + wr_ * (TBM / 2) + mr * 16 + (lane >> 4) * 4 + r;
        if (grow < M) {
          float o = acc[mr][nr][r] + bsv;
          if constexpr (OUTMODE == OUT_VSLAB) {
            int b = grow >= NQ;
            int n = grow - (b ? NQ : 0);
            int hh = col >> 5, d = col & 31;
            Cb[((size_t)(hh * 2 + b) * NQ + n) * 32 + d] = f2bf(o);
          } else if constexpr (OUTMODE == OUT_CONV) {
            int hh, j;
            if (col < 128) { hh = col >> 4; j = col & 15; }
            else { int c = col - 128; hh = c >> 3; j = 16 + (c & 7); }
            Cf[((size_t)hh * NQ + grow) * 24 + j] = o;
          } else if constexpr (OUTMODE == OUT_F32ADD) {
            o += addend[(size_t)grow * 256 + col];
            Cf[(size_t)grow * 256 + col] = o;
          } else {
            Cf[(size_t)grow * 256 + col] = o;
          }
        }
      }
    }
  }
}

// ---------------------------------------------------------------------------
// sample v3: blockIdx = q*8 + h  (h pins the block's XCD via id%8 heuristic:
// each XCD's random gathers touch only head h's 5.1 MB valp slab -> L2-hot).
// Wave: 8 queries x 8 lanes; lane g covers channels g*4..g*4+3 of head h.
// convall: [h][n][24] = {offsets b0 (8), offsets b1 (8), logits b0 (4), b1 (4)}
// valpb:   [(h*2+b)][n][32]
// ---------------------------------------------------------------------------
__global__ __launch_bounds__(256) void sample_kernel(
    const short* __restrict__ valpb, const float* __restrict__ convall,
    const float* __restrict__ preref, const float* __restrict__ refp,
    short* __restrict__ midb)
{
  int id = blockIdx.x;
  int h = id & 7, q = id >> 3;
  int wv = threadIdx.x >> 6, lane = threadIdx.x & 63;
  int n = q * 32 + wv * 8 + (lane >> 3);
  int g = lane & 7;

  const float* cv = convall + ((size_t)h * NQ + n) * 24;
  f32x4 acc = (f32x4){0.f, 0.f, 0.f, 0.f};

#pragma unroll
  for (int b = 0; b < 2; b++) {
    const float* rp = b ? refp : preref;
    float rx = rp[(size_t)n * 2 + 0] * 200.f - 0.5f;
    float ry = rp[(size_t)n * 2 + 1] * 200.f - 0.5f;

    float4 o01 = *(const float4*)(cv + b * 8);
    float4 o23 = *(const float4*)(cv + b * 8 + 4);
    float ox[4] = {o01.x, o01.z, o23.x, o23.z};
    float oy[4] = {o01.y, o01.w, o23.y, o23.w};

    float4 a = *(const float4*)(cv + 16 + b * 4);
    float mx = fmaxf(fmaxf(a.x, a.y), fmaxf(a.z, a.w));
    float e0 = __expf(a.x - mx), e1 = __expf(a.y - mx);
    float e2 = __expf(a.z - mx), e3 = __expf(a.w - mx);
    float inv = 1.f / (e0 + e1 + e2 + e3);
    float aw[4] = {e0 * inv, e1 * inv, e2 * inv, e3 * inv};

    const short* vb = valpb + ((size_t)(h * 2 + b) * NQ) * 32 + g * 4;

#pragma unroll
    for (int p = 0; p < 4; p++) {
      float x = rx + ox[p];
      float y = ry + oy[p];
      float x0f = floorf(x), y0f = floorf(y);
      float fx = x - x0f, fy = y - y0f;
      int x0 = (int)x0f, y0 = (int)y0f;
      float wt[4] = {(1.f - fx) * (1.f - fy), fx * (1.f - fy),
                     (1.f - fx) * fy, fx * fy};
      int xs[4] = {x0, x0 + 1, x0, x0 + 1};
      int ys[4] = {y0, y0, y0 + 1, y0 + 1};
#pragma unroll
      for (int c = 0; c < 4; c++) {
        if (xs[c] >= 0 && xs[c] < BEVW && ys[c] >= 0 && ys[c] < BEVH) {
          bf16x4 v = *(const bf16x4*)&vb[(size_t)(ys[c] * BEVW + xs[c]) * 32];
          float cw = aw[p] * wt[c];
          acc[0] += cw * bf2f(v[0]);
          acc[1] += cw * bf2f(v[1]);
          acc[2] += cw * bf2f(v[2]);
          acc[3] += cw * bf2f(v[3]);
        }
      }
    }
  }

  bf16x4 m4;
#pragma unroll
  for (int j = 0; j < 4; j++) m4[j] = f2bf(acc[j] * 0.5f);
  *(bf16x4*)&midb[(size_t)n * 256 + h * 32 + g * 4] = m4;
}

// ---------------------------------------------------------------------------
extern "C" void kernel_launch(void* const* d_in, const int* in_sizes, int n_in,
                              void* d_out, int out_size, void* d_ws, size_t ws_size,
                              hipStream_t stream)
{
  const float* query  = (const float*)d_in[0];
  const float* qpos   = (const float*)d_in[3];
  const float* refp   = (const float*)d_in[4];
  const float* prebev = (const float*)d_in[7];
  const float* preref = (const float*)d_in[8];
  const unsigned char* sos = (const unsigned char*)d_in[9];
  const float* Wv     = (const float*)d_in[10];
  const float* bv     = (const float*)d_in[11];
  const float* Wo     = (const float*)d_in[12];
  const float* bo     = (const float*)d_in[13];
  const float* off_w  = (const float*)d_in[14];
  const float* off_b  = (const float*)d_in[15];
  const float* attn_w = (const float*)d_in[16];
  const float* attn_b = (const float*)d_in[17];
  float* out = (float*)d_out;

  // workspace layout
  float* convall = (float*)d_ws;                    // 8*40000*24 = 7,680,000 f
  short* valpb  = (short*)(convall + 7680000);      // 16*40000*32 = 20,480,000 s
  short* img    = valpb + 20480000;                 // 203*202*512 = 20,996,672 s
  short* qbf    = img + 20996672;                   // 40000*256 = 10,240,000 s
  short* midb   = qbf + 10240000;                   // 40000*256 = 10,240,000 s
  short* wcat   = midb + 10240000;                  // 192*4608 = 884,736 s
  short* wvb    = wcat + 884736;                    // 65,536 s
  short* wob    = wvb + 65536;                      // 65,536 s
  float* bcat   = (float*)(wob + 65536);            // 192 f

  pad_kernel<<<dim3((203 * 202 * 64 + 255) / 256), dim3(256), 0, stream>>>(
      query, qpos, prebev, sos, img, qbf);
  reorder_cat_kernel<<<dim3((192 * 4608 + 255) / 256), dim3(256), 0, stream>>>(
      off_w, off_b, attn_w, attn_b, wcat, bcat);
  wcast_kernel<<<dim3(64), dim3(256), 0, stream>>>(Wv, Wo, wvb, wob);

  // valp(bf16 slabs) = val @ Wv^T + bv   (M=80000, N=256, K=256)
  mfma_gemm_kernel<A_VAL, 256, 128, 64, OUT_VSLAB>
      <<<dim3(625, 4), dim3(256), 0, stream>>>(
      img, qbf, wvb, bv, nullptr, nullptr, valpb, 2 * NQ);

  // merged convs (M=40000, N=192, K=4608) -> convall [h][n][24]
  mfma_gemm_kernel<A_IM2COL, 4608, 64, 192, OUT_CONV>
      <<<dim3(625, 1), dim3(256), 0, stream>>>(
      img, nullptr, wcat, bcat, nullptr, convall, nullptr, NQ);

  // softmax + bilinear sampling + queue average -> midb bf16
  sample_kernel<<<dim3(10000), dim3(256), 0, stream>>>(
      valpb, convall, preref, refp, midb);

  // out = mid @ Wo^T + bo + identity   (M=40000, N=256, K=256) -> fp32
  mfma_gemm_kernel<A_PLAIN, 256, 128, 64, OUT_F32ADD>
      <<<dim3(313, 4), dim3(256), 0, stream>>>(
      midb, nullptr, wob, bo, query, out, nullptr, NQ);

  (void)in_sizes; (void)n_in; (void)out_size; (void)ws_size;
}